// Round 9
// baseline (169.320 us; speedup 1.0000x reference)
//
#include <hip/hip_runtime.h>
#include <hip/hip_bf16.h>
#include <string.h>

// Problem constants
#define NB    4096      // batch rows
#define IND_  512       // feature dim
#define OUTD_ 512       // output dim (GEMM M, "o")
#define XCOLS 514       // P + IND
#define ND    25        // D^P
#define KTOT  12800     // IND_*ND
#define NSPL  4         // split over 4 i-windows

// Wt (fragment-order W) geometry: Wt[d][og][iw][lane][32]
//   d in [0,25), og in [0,32) (16-row o-groups), iw in [0,4), lane in [0,64)
//   d-stride = 32*4*2048 = 262144; bias block at WT_BIAS + og*2048
#define WT_DS   262144
#define WT_BIAS 6553600   // 25*262144; +32*2048 = 6,619,136 total

// GEMM tiling (v11: 32x128 block, 4 waves x (16o x 64b), ALL-REGISTER,
//              ~120 regs/wave -> 4 waves/SIMD, depth-3 prefetch)
#define BM 32
#define BN 128

// prep_w tiling (R18-proven v2 load stage)
#define PWI 64
#define PWO 4
#define PWC (PWO * ND)   // 100 columns (o_l*25 + d)
#define T8P 112          // tile8 padded byte stride

typedef float  f32x4  __attribute__((ext_vector_type(4)));
typedef int    i32x4  __attribute__((ext_vector_type(4)));
typedef int    i32x8  __attribute__((ext_vector_type(8)));
typedef unsigned short u16x4 __attribute__((ext_vector_type(4)));
typedef unsigned int   u32x2 __attribute__((ext_vector_type(2)));

__device__ __forceinline__ unsigned short f2bf(float f) {
  unsigned int x = __float_as_uint(f);
  return (unsigned short)((x + 0x7fffu + ((x >> 16) & 1u)) >> 16);
}

__device__ __forceinline__ float bf2f(unsigned short u) {
  return __uint_as_float(((unsigned int)u) << 16);
}

__device__ __forceinline__ unsigned int pk_bf16(float a, float b) {
  return (unsigned int)f2bf(a) | ((unsigned int)f2bf(b) << 16);
}

// Software fp32 -> OCP e4m3fn, RNE, for v >= 0 (all values < 1.2).
__device__ __forceinline__ unsigned char f2fp8(float v) {
  if (v < 0.015625f) {
    return (unsigned char)__float2int_rn(v * 512.0f);
  }
  unsigned int u = __float_as_uint(v);
  u += 0x7ffffu + ((u >> 20) & 1u);
  int e = (int)(u >> 23) - 127 + 7;
  unsigned int m = (u >> 20) & 7u;
  return (unsigned char)((e << 3) | m);
}

__device__ __forceinline__ float basis_f(float t, int j) {
  switch (j) {
    case 0: return 1.0f;
    case 1: return t;
    case 2: return t * t;
    case 3: { float r = t - 0.33f; r = r > 0.0f ? r : 0.0f; return r * r; }
    default:{ float r = t - 0.66f; r = r > 0.0f ? r : 0.0f; return r * r; }
  }
}

// ---------------------------------------------------------------------------
// prep_all v4 (R7/R8-proven, unchanged): fragment-order Wt, fragment-order
// kbDT [d][bt][l15][nf], bias block in Wt.
// ---------------------------------------------------------------------------
__global__ __launch_bounds__(256) void prep_all_kernel(
    const float* __restrict__ x, const float* __restrict__ W,
    const float* __restrict__ bias, unsigned char* __restrict__ Xf8,
    float* __restrict__ kbDT, unsigned char* __restrict__ kbT8,
    unsigned char* __restrict__ Wt, float* __restrict__ out)
{
  __shared__ unsigned char tile8[PWI * T8P];   // 7 KB
  const int bid = blockIdx.x;
  const int tid = threadIdx.x;

  if (bid < 512) {
    const int lane = tid & 63;
    #pragma unroll
    for (int rr = 0; rr < 2; ++rr) {
      const int b = bid * 8 + (tid >> 6) * 2 + rr;
      const float* xr = x + (size_t)b * XCOLS;
      const float* fp = xr + 2 + lane * 8;
      float2 a0 = *(const float2*)(fp + 0);
      float2 a1 = *(const float2*)(fp + 2);
      float2 a2 = *(const float2*)(fp + 4);
      float2 a3 = *(const float2*)(fp + 6);
      float xf[8] = {a0.x, a0.y, a1.x, a1.y, a2.x, a2.y, a3.x, a3.y};
      u32x2 pk;
      pk[0] = (unsigned int)f2fp8(xf[0]) | ((unsigned int)f2fp8(xf[1]) << 8) |
              ((unsigned int)f2fp8(xf[2]) << 16) | ((unsigned int)f2fp8(xf[3]) << 24);
      pk[1] = (unsigned int)f2fp8(xf[4]) | ((unsigned int)f2fp8(xf[5]) << 8) |
              ((unsigned int)f2fp8(xf[6]) << 16) | ((unsigned int)f2fp8(xf[7]) << 24);
      *reinterpret_cast<u32x2*>(Xf8 + (size_t)b * IND_ + lane * 8) = pk;

      float t0 = xr[0], t1 = xr[1];
      if (lane < 2) out[(size_t)b * XCOLS + lane] = (lane == 0) ? t0 : t1;
      {
        // telescoping difference dk_d = kv_d - kv_{d+1} (kv_25 := 0),
        // stored as kbDT[((d*32 + bt)*16 + (b&15))*8 + ((b>>4)&7)]
        int d1 = lane / 5, d2 = lane - d1 * 5;
        float kvd = basis_f(t0, d1) * basis_f(t1, d2);
        float kvn = 0.0f;
        if (lane < 24) {
          int e1 = (lane + 1) / 5, e2 = (lane + 1) - e1 * 5;
          kvn = basis_f(t0, e1) * basis_f(t1, e2);
        }
        if (lane < ND) {
          int bt = b >> 7, bl = b & 15, nf = (b >> 4) & 7;
          kbDT[(((size_t)lane * 32 + bt) * 16 + bl) * 8 + nf] = kvd - kvn;
        }
      }
      {
        int ta = 2 * lane, tb = 2 * lane + 1;
        unsigned char ba = 0, bb = 0;
        if (ta < ND) { int d1 = ta / 5, d2 = ta - d1 * 5;
                       ba = f2fp8(basis_f(t0, d1) * basis_f(t1, d2)); }
        if (tb < ND) { int d1 = tb / 5, d2 = tb - d1 * 5;
                       bb = f2fp8(basis_f(t0, d1) * basis_f(t1, d2)); }
        *(unsigned short*)(kbT8 + (size_t)b * 128 + 2 * lane) =
            (unsigned short)ba | ((unsigned short)bb << 8);
      }
    }
  } else {
    const int pw = bid - 512;
    const int i0 = (pw & 7) * PWI;
    const int o0 = (pw >> 3) * PWO;

    for (int t = tid; t < PWI * (PWC / 4); t += 256) {
      int il = t / (PWC / 4);
      int c4 = t - il * (PWC / 4);
      float4 v = *(const float4*)(W + ((size_t)(i0 + il) * OUTD_ + o0) * ND + c4 * 4);
      unsigned int pk = (unsigned int)f2fp8(v.x) | ((unsigned int)f2fp8(v.y) << 8) |
                        ((unsigned int)f2fp8(v.z) << 16) | ((unsigned int)f2fp8(v.w) << 24);
      *(unsigned int*)&tile8[il * T8P + c4 * 4] = pk;
    }
    __syncthreads();

    // byte-gather into FRAGMENT-ORDER Wt:
    //   dest(d, o, ib) = (((d*32 + o>>4)*4 + ib>>7)*2048
    //                    + ((ib&127)>>5)*512 + (o&15)*32 + (ib&31)
    for (int g = tid; g < PWC * (PWI / 8); g += 256) {
      int c  = g >> 3;
      int ig = g & 7;
      int d  = c % 25;
      int o_l = c / 25;
      unsigned long long v = 0;
      #pragma unroll
      for (int jj = 0; jj < 8; ++jj)
        v |= (unsigned long long)tile8[(ig * 8 + jj) * T8P + c] << (8 * jj);
      int o  = o0 + o_l;
      int ib = i0 + ig * 8;            // [0,512)
      int iw = ib >> 7;
      int wb = ib & 127;
      size_t dest = (((size_t)d * 32 + (o >> 4)) * 4 + iw) * 2048
                  + (size_t)(((wb >> 5) * 16 + (o & 15)) * 32 + (wb & 31));
      *reinterpret_cast<unsigned long long*>(Wt + dest) = v;
    }

    if ((pw & 7) == 0) {
      // bias block: fragment order at WT_BIAS + og*2048
      int o = o0 + (tid >> 6);
      int p = tid & 63;
      int ta = 2 * p, tb = 2 * p + 1;
      unsigned char ba = (ta < ND) ? f2fp8(bias[o * ND + ta]) : (unsigned char)0;
      unsigned char bb = (tb < ND) ? f2fp8(bias[o * ND + tb]) : (unsigned char)0;
      size_t dest = WT_BIAS + (size_t)(o >> 4) * 2048
                  + (size_t)(((ta >> 5) * 16 + (o & 15)) * 32 + (ta & 31));
      *(unsigned short*)(Wt + dest) =
          (unsigned short)ba | ((unsigned short)bb << 8);
    }
  }
}

// ---------------------------------------------------------------------------
// gemm_mx v11: half-wave tile -> 4 waves/SIMD TLP.
//
// R26 post-mortem of v10: ~42 us — exactly where the barrier-locked LDS
// variant (v5) converged.  Two maximally different schedules at the same
// number, both with MFMA-busy ~= the 11.5 us floor, both at 2 waves/SIMD.
// The shared limiter is thin TLP: at 2 waves/SIMD all latency (L2 ~200,
// HBM first-touch ~900, MFMA result latency into the flush chain) must be
// covered by in-wave ILP, and ~70% of the MFMA pipe idles.
//
// v11: wave tile 16o x 64b (half of v10).  Regs: bfr[4] 32 + a0/a1/a2 24
// + dk 4 + ptrs/temps ~25 ~= 88 arch + acc[4]+fin[4] 32 = ~120 total
// <= 128 cap -> 4 waves/SIMD (__launch_bounds__(256,4); m69: occupancy
// steps at 128).  Per-SIMD: 4 waves x 4 MFMA x 34.5 = 552 cyc/iter (floor
// unchanged: 2 rounds x 25 x 552 = 11.5 us), but each wave occupies only
// ~180 of those 552 -> 3x issue slack per wave, per-wave VMEM halved.
// Paired waves (w, w^1) read the SAME A-fragment -> L1 dedup, A-traffic
// flat.  Block = 4 waves = 32o x 128b; grid = 16(ox) x 4(iw) x 32(by)
// = 2048 -> 4 resident blocks/CU (16 waves/CU, 50% occ), 2 rounds.
// XCD map: xcd = id&7 -> ox pair {2k, 2k+1}: per-XCD A working set
// 2 ox x 4 iw x 100 KB = 800 KB + Xf8 2 MB (L2-resident).
// Everything else v10-proven: coalesced fragment-order A, dk dwordx4,
// telescoping flush, depth-3 rotation, harmless in-ws A overrun.
// SPILL TRIPWIRE: if WRITE_SIZE > 17 MB next round, the 128-cap spilled.
// ---------------------------------------------------------------------------
__global__ __launch_bounds__(256, 4) void gemm_mx_kernel(
    const unsigned char* __restrict__ Wt, const unsigned char* __restrict__ Xf8,
    const float* __restrict__ kbDT, const unsigned char* __restrict__ kbT8,
    unsigned short* __restrict__ Pb)
{
  const int tid  = threadIdx.x;
  const int lane = tid & 63;
  const int w    = tid >> 6;            // [0,4)
  const int l15  = lane & 15;
  const int quad = lane >> 4;

  const int id  = blockIdx.x;           // [0,2048)
  const int ox  = ((id & 7) << 1) | ((id >> 3) & 1);  // [0,16), XCD-paired
  const int iw  = (id >> 4) & 3;        // i-window (split) [0,4)
  const int by  = id >> 6;              // b-tile [0,32)

  const int o0 = ox * BM;               // 32-row o-tile base
  const int b0 = by * BN;
  const bool tail = (iw == 3);

  const int og = ox * 2 + (w >> 1);     // global 16-row o-group [0,32)
  const int bh = w & 1;                 // b-half (64 cols)

  // helper: load a 32-B fragment into i32x8
  auto load8 = [](const unsigned char* p) -> i32x8 {
    i32x4 lo = *reinterpret_cast<const i32x4*>(p);
    i32x4 hi = *reinterpret_cast<const i32x4*>(p + 16);
    i32x8 v;
    v[0] = lo[0]; v[1] = lo[1]; v[2] = lo[2]; v[3] = lo[3];
    v[4] = hi[0]; v[5] = hi[1]; v[6] = hi[2]; v[7] = hi[3];
    return v;
  };

  // ---- B fragments once (held for the whole kernel): 32 regs ----
  i32x8 bfr[4];
  #pragma unroll
  for (int nf = 0; nf < 4; ++nf)
    bfr[nf] = load8(Xf8 + (size_t)(b0 + bh * 64 + nf * 16 + l15) * IND_
                        + iw * 128 + quad * 32);

  // ---- A pointer: fragment-order, contiguous per og; +WT_DS per iter ----
  const unsigned char* aP =
      Wt + ((size_t)og * 4 + iw) * 2048 + lane * 32;

  // ---- dk pointer: kbDT[((d*32+by)*16+l15)*8 + bh*4]; +4096 per d ----
  const float* dP = kbDT + (((size_t)by * 16 + l15) * 8) + bh * 4;

  f32x4 acc[4], fin[4];
  #pragma unroll
  for (int nf = 0; nf < 4; ++nf) { acc[nf] = (f32x4)0.0f; fin[nf] = (f32x4)0.0f; }

  // 4 MFMAs (telescoping: acc never reset) + dk-scaled flush into fin
  auto mfma_flush = [&](const i32x8& a, const f32x4& q) {
    #pragma unroll
    for (int nf = 0; nf < 4; ++nf)
      acc[nf] = __builtin_amdgcn_mfma_scale_f32_16x16x128_f8f6f4(
          a, bfr[nf], acc[nf], 0, 0, 0, 0x7f7f7f7f, 0, 0x7f7f7f7f);
    #pragma unroll
    for (int nf = 0; nf < 4; ++nf)
      #pragma unroll
      for (int r = 0; r < 4; ++r)
        fin[nf][r] += q[nf] * acc[nf][r];
  };

  // ---- prologue: A(0), A(1) in flight ----
  i32x8 a0 = load8(aP);
  i32x8 a1 = load8(aP + WT_DS);
  i32x8 a2;

  // ---- main loop: 24 iters in 8 unrolled-3 passes, static triple-buffer.
  // Pass invariant: a0 = A(n), a1 = A(n+1) in flight; dP at d = n.
  for (int pass = 0; pass < 8; ++pass) {
    a2 = load8(aP + 2 * WT_DS);                        // A(n+2)
    f32x4 q = *reinterpret_cast<const f32x4*>(dP);
    mfma_flush(a0, q);

    a0 = load8(aP + 3 * WT_DS);                        // A(n+3)
    q = *reinterpret_cast<const f32x4*>(dP + 4096);
    mfma_flush(a1, q);

    a1 = load8(aP + 4 * WT_DS);                        // A(n+4); last pass
    q = *reinterpret_cast<const f32x4*>(dP + 8192);    //   reads the bias
    mfma_flush(a2, q);                                 //   block — unused

    aP += 3 * WT_DS;
    dP += 12288;
  }

  // ---- peeled iter 24 (a0 = A(24)); bias-A reload for iw==3 ----
  if (tail) a1 = load8(Wt + WT_BIAS + (size_t)og * 2048 + lane * 32);
  {
    f32x4 q = *reinterpret_cast<const f32x4*>(dP);
    mfma_flush(a0, q);
  }

  // ---- bias K-tail (iw==3): B = kbT8 fragments, accumulate into fin ----
  if (tail) {
    i32x8 bft[4];
    #pragma unroll
    for (int nf = 0; nf < 4; ++nf)
      bft[nf] = load8(kbT8 + (size_t)(b0 + bh * 64 + nf * 16 + l15) * 128
                           + quad * 32);
    #pragma unroll
    for (int nf = 0; nf < 4; ++nf)
      fin[nf] = __builtin_amdgcn_mfma_scale_f32_16x16x128_f8f6f4(
          a1, bft[nf], fin[nf], 0, 0, 0, 0x7f7f7f7f, 0, 0x7f7f7f7f);
  }

  // ---- store partial as bf16 ----
  unsigned short* Pz = Pb + (size_t)iw * NB * OUTD_;
  #pragma unroll
  for (int nf = 0; nf < 4; ++nf) {
    int bg = b0 + bh * 64 + nf * 16 + l15;
    int oo = o0 + (w >> 1) * 16 + quad * 4;
    u32x2 pk;
    pk[0] = pk_bf16(fin[nf][0], fin[nf][1]);
    pk[1] = pk_bf16(fin[nf][2], fin[nf][3]);
    *reinterpret_cast<u32x2*>(&Pz[(size_t)bg * OUTD_ + oo]) = pk;
  }
}

// ---------------------------------------------------------------------------
// epilogue: out[b][2+o..2+o+3] = relu(P0+P1+P2+P3)  (bias in K-tail)
// ---------------------------------------------------------------------------
__global__ __launch_bounds__(256) void epilogue_kernel(
    const unsigned short* __restrict__ Pb, float* __restrict__ out)
{
  const int idx = (blockIdx.x * 256 + threadIdx.x) * 4;   // < 4096*512
  const int b = idx >> 9;
  const int o = idx & 511;
  const size_t ps = (size_t)NB * OUTD_;
  float s[4] = {0.0f, 0.0f, 0.0f, 0.0f};
  #pragma unroll
  for (int z = 0; z < NSPL; ++z) {
    u16x4 v = *reinterpret_cast<const u16x4*>(&Pb[z * ps + idx]);
    #pragma unroll
    for (int e = 0; e < 4; ++e) s[e] += bf2f(v[e]);
  }
  float* op = out + (size_t)b * XCOLS + 2 + o;   // 8B-aligned
  float2 lo, hi;
  lo.x = s[0] > 0.0f ? s[0] : 0.0f;
  lo.y = s[1] > 0.0f ? s[1] : 0.0f;
  hi.x = s[2] > 0.0f ? s[2] : 0.0f;
  hi.y = s[3] > 0.0f ? s[3] : 0.0f;
  *(float2*)op = lo;
  *(float2*)(op + 2) = hi;
}

// ---------------------------------------------------------------------------
extern "C" void kernel_launch(void* const* d_in, const int* in_sizes, int n_in,
                              void* d_out, int out_size, void* d_ws, size_t ws_size,
                              hipStream_t stream) {
  const float* x    = (const float*)d_in[0];   // 4096 x 514
  const float* W    = (const float*)d_in[1];   // 512 x 512 x 25
  const float* bias = (const float*)d_in[2];   // 512 x 25
  float* out = (float*)d_out;
  char* ws = (char*)d_ws;

  // ws layout (bytes):
  //   Xf8 2,097,152 | Wt 6,619,136 | kbDT 25*4096*4 = 409,600
  //   kbT8 524,288 | Pb 4*4096*512*2 = 16,777,216   (total ~26.4 MB)
  const size_t xf_off  = 0;
  const size_t wf_off  = 2097152;
  const size_t kb_off  = wf_off + 6619136;
  const size_t kbt_off = kb_off + 409600;
  const size_t p_off   = kbt_off + (size_t)NB * 128;
  unsigned char* Xf8  = (unsigned char*)(ws + xf_off);
  unsigned char* Wt   = (unsigned char*)(ws + wf_off);
  float* kbDT         = (float*)(ws + kb_off);
  unsigned char* kbT8 = (unsigned char*)(ws + kbt_off);
  unsigned short* Pb  = (unsigned short*)(ws + p_off);

  prep_all_kernel<<<1536, 256, 0, stream>>>(x, W, bias, Xf8, kbDT, kbT8, Wt, out);
  gemm_mx_kernel<<<2048, 256, 0, stream>>>(Wt, Xf8, kbDT, kbT8, Pb);
  epilogue_kernel<<<(NB * OUTD_) / 1024, 256, 0, stream>>>(Pb, out);
}

// Round 11
// 129.086 us; speedup vs baseline: 1.3117x; 1.3117x over previous
//
#include <hip/hip_runtime.h>
#include <hip/hip_bf16.h>
#include <string.h>

// Problem constants
#define NB    4096      // batch rows
#define IND_  512       // feature dim
#define OUTD_ 512       // output dim (GEMM M, "o")
#define XCOLS 514       // P + IND
#define ND    25        // D^P
#define KTOT  12800     // IND_*ND
#define NSPL  4         // split over 4 i-windows

// Wt (fragment-order W) geometry: Wt[d][og][iw][lane][32]
//   d in [0,25), og in [0,32) (16-row o-groups), iw in [0,4), lane in [0,64)
//   d-stride = 32*4*2048 = 262144; bias block at WT_BIAS + og*2048
#define WT_DS   262144
#define WT_BIAS 6553600   // 25*262144; +32*2048 = 6,619,136 total

// GEMM tiling (v12: 32x128 block, 4 waves x (16o x 64b), ALL-REGISTER,
//              (256,3) slack budget, depth-3 A + depth-2 dk prefetch)
#define BM 32
#define BN 128

// prep_w tiling (R18-proven v2 load stage)
#define PWI 64
#define PWO 4
#define PWC (PWO * ND)   // 100 columns (o_l*25 + d)
#define T8P 112          // tile8 padded byte stride

typedef float  f32x4  __attribute__((ext_vector_type(4)));
typedef int    i32x4  __attribute__((ext_vector_type(4)));
typedef int    i32x8  __attribute__((ext_vector_type(8)));
typedef unsigned short u16x4 __attribute__((ext_vector_type(4)));
typedef unsigned int   u32x2 __attribute__((ext_vector_type(2)));

__device__ __forceinline__ unsigned short f2bf(float f) {
  unsigned int x = __float_as_uint(f);
  return (unsigned short)((x + 0x7fffu + ((x >> 16) & 1u)) >> 16);
}

__device__ __forceinline__ float bf2f(unsigned short u) {
  return __uint_as_float(((unsigned int)u) << 16);
}

__device__ __forceinline__ unsigned int pk_bf16(float a, float b) {
  return (unsigned int)f2bf(a) | ((unsigned int)f2bf(b) << 16);
}

// Software fp32 -> OCP e4m3fn, RNE, for v >= 0 (all values < 1.2).
__device__ __forceinline__ unsigned char f2fp8(float v) {
  if (v < 0.015625f) {
    return (unsigned char)__float2int_rn(v * 512.0f);
  }
  unsigned int u = __float_as_uint(v);
  u += 0x7ffffu + ((u >> 20) & 1u);
  int e = (int)(u >> 23) - 127 + 7;
  unsigned int m = (u >> 20) & 7u;
  return (unsigned char)((e << 3) | m);
}

__device__ __forceinline__ float basis_f(float t, int j) {
  switch (j) {
    case 0: return 1.0f;
    case 1: return t;
    case 2: return t * t;
    case 3: { float r = t - 0.33f; r = r > 0.0f ? r : 0.0f; return r * r; }
    default:{ float r = t - 0.66f; r = r > 0.0f ? r : 0.0f; return r * r; }
  }
}

// ---------------------------------------------------------------------------
// prep_all v4 (R7/R8-proven, unchanged): fragment-order Wt, fragment-order
// kbDT [d][bt][l15][nf], bias block in Wt.
// ---------------------------------------------------------------------------
__global__ __launch_bounds__(256) void prep_all_kernel(
    const float* __restrict__ x, const float* __restrict__ W,
    const float* __restrict__ bias, unsigned char* __restrict__ Xf8,
    float* __restrict__ kbDT, unsigned char* __restrict__ kbT8,
    unsigned char* __restrict__ Wt, float* __restrict__ out)
{
  __shared__ unsigned char tile8[PWI * T8P];   // 7 KB
  const int bid = blockIdx.x;
  const int tid = threadIdx.x;

  if (bid < 512) {
    const int lane = tid & 63;
    #pragma unroll
    for (int rr = 0; rr < 2; ++rr) {
      const int b = bid * 8 + (tid >> 6) * 2 + rr;
      const float* xr = x + (size_t)b * XCOLS;
      const float* fp = xr + 2 + lane * 8;
      float2 a0 = *(const float2*)(fp + 0);
      float2 a1 = *(const float2*)(fp + 2);
      float2 a2 = *(const float2*)(fp + 4);
      float2 a3 = *(const float2*)(fp + 6);
      float xf[8] = {a0.x, a0.y, a1.x, a1.y, a2.x, a2.y, a3.x, a3.y};
      u32x2 pk;
      pk[0] = (unsigned int)f2fp8(xf[0]) | ((unsigned int)f2fp8(xf[1]) << 8) |
              ((unsigned int)f2fp8(xf[2]) << 16) | ((unsigned int)f2fp8(xf[3]) << 24);
      pk[1] = (unsigned int)f2fp8(xf[4]) | ((unsigned int)f2fp8(xf[5]) << 8) |
              ((unsigned int)f2fp8(xf[6]) << 16) | ((unsigned int)f2fp8(xf[7]) << 24);
      *reinterpret_cast<u32x2*>(Xf8 + (size_t)b * IND_ + lane * 8) = pk;

      float t0 = xr[0], t1 = xr[1];
      if (lane < 2) out[(size_t)b * XCOLS + lane] = (lane == 0) ? t0 : t1;
      {
        // telescoping difference dk_d = kv_d - kv_{d+1} (kv_25 := 0),
        // stored as kbDT[((d*32 + bt)*16 + (b&15))*8 + ((b>>4)&7)]
        int d1 = lane / 5, d2 = lane - d1 * 5;
        float kvd = basis_f(t0, d1) * basis_f(t1, d2);
        float kvn = 0.0f;
        if (lane < 24) {
          int e1 = (lane + 1) / 5, e2 = (lane + 1) - e1 * 5;
          kvn = basis_f(t0, e1) * basis_f(t1, e2);
        }
        if (lane < ND) {
          int bt = b >> 7, bl = b & 15, nf = (b >> 4) & 7;
          kbDT[(((size_t)lane * 32 + bt) * 16 + bl) * 8 + nf] = kvd - kvn;
        }
      }
      {
        int ta = 2 * lane, tb = 2 * lane + 1;
        unsigned char ba = 0, bb = 0;
        if (ta < ND) { int d1 = ta / 5, d2 = ta - d1 * 5;
                       ba = f2fp8(basis_f(t0, d1) * basis_f(t1, d2)); }
        if (tb < ND) { int d1 = tb / 5, d2 = tb - d1 * 5;
                       bb = f2fp8(basis_f(t0, d1) * basis_f(t1, d2)); }
        *(unsigned short*)(kbT8 + (size_t)b * 128 + 2 * lane) =
            (unsigned short)ba | ((unsigned short)bb << 8);
      }
    }
  } else {
    const int pw = bid - 512;
    const int i0 = (pw & 7) * PWI;
    const int o0 = (pw >> 3) * PWO;

    for (int t = tid; t < PWI * (PWC / 4); t += 256) {
      int il = t / (PWC / 4);
      int c4 = t - il * (PWC / 4);
      float4 v = *(const float4*)(W + ((size_t)(i0 + il) * OUTD_ + o0) * ND + c4 * 4);
      unsigned int pk = (unsigned int)f2fp8(v.x) | ((unsigned int)f2fp8(v.y) << 8) |
                        ((unsigned int)f2fp8(v.z) << 16) | ((unsigned int)f2fp8(v.w) << 24);
      *(unsigned int*)&tile8[il * T8P + c4 * 4] = pk;
    }
    __syncthreads();

    // byte-gather into FRAGMENT-ORDER Wt:
    //   dest(d, o, ib) = (((d*32 + o>>4)*4 + ib>>7)*2048
    //                    + ((ib&127)>>5)*512 + (o&15)*32 + (ib&31)
    for (int g = tid; g < PWC * (PWI / 8); g += 256) {
      int c  = g >> 3;
      int ig = g & 7;
      int d  = c % 25;
      int o_l = c / 25;
      unsigned long long v = 0;
      #pragma unroll
      for (int jj = 0; jj < 8; ++jj)
        v |= (unsigned long long)tile8[(ig * 8 + jj) * T8P + c] << (8 * jj);
      int o  = o0 + o_l;
      int ib = i0 + ig * 8;            // [0,512)
      int iw = ib >> 7;
      int wb = ib & 127;
      size_t dest = (((size_t)d * 32 + (o >> 4)) * 4 + iw) * 2048
                  + (size_t)(((wb >> 5) * 16 + (o & 15)) * 32 + (wb & 31));
      *reinterpret_cast<unsigned long long*>(Wt + dest) = v;
    }

    if ((pw & 7) == 0) {
      // bias block: fragment order at WT_BIAS + og*2048
      int o = o0 + (tid >> 6);
      int p = tid & 63;
      int ta = 2 * p, tb = 2 * p + 1;
      unsigned char ba = (ta < ND) ? f2fp8(bias[o * ND + ta]) : (unsigned char)0;
      unsigned char bb = (tb < ND) ? f2fp8(bias[o * ND + tb]) : (unsigned char)0;
      size_t dest = WT_BIAS + (size_t)(o >> 4) * 2048
                  + (size_t)(((ta >> 5) * 16 + (o & 15)) * 32 + (ta & 31));
      *(unsigned short*)(Wt + dest) =
          (unsigned short)ba | ((unsigned short)bb << 8);
    }
  }
}

// ---------------------------------------------------------------------------
// gemm_mx v12 (RESUBMIT — R10 was an infra failure, no signal): v11
// half-tile with a SLACK register budget + dk prefetch.
//
// R27 post-mortem of v11: (256,4) set a 128-total cap and the allocator
// split it 64 arch / 64 AGPR (accum block rounded up), leaving 64 arch
// slots for an ~88-arch demand -> ~24 regs spilled (VGPR_Count 64, WRITE
// 68.7 MB).  Occupancy DID rise to 31.7%.  Allocator ledger R4/R7/R9:
// any bound whose cap sits at/below demand squeezes arch regs and spills;
// clean only with real slack (R6/R8 at cap 256).
//
// v12: same 16o x 64b wave tile (demand ~125 total incl. 32 acc) with
// __launch_bounds__(256,3): cap 170, slack ~45 -> no squeeze, >=3 waves/
// SIMD guaranteed, 4 if the allocation lands <=128.  Plus the one load
// with ZERO prefetch distance is fixed: dk(q) now rotates through 3 regs
// loaded one iteration ahead (was: loaded and consumed in the same iter,
// exposing ~200cyc L2 latency after the MFMA block every iter).
// Everything else R8/R9-proven: coalesced fragment-order A (depth-3
// rotation), telescoping flush, bias tail, harmless in-ws A overrun.
// SPILL TRIPWIRE: WRITE_SIZE > 17 MB => squeezed again.
// FALSIFIER (pre-committed): clean WRITE + occupancy >=35% + gemm >=38us
// => TLP/latency family exhausted; next round goes algorithmic
// (pre-scaled Xs, flush-free pure GEMM).
// ---------------------------------------------------------------------------
__global__ __launch_bounds__(256, 3) void gemm_mx_kernel(
    const unsigned char* __restrict__ Wt, const unsigned char* __restrict__ Xf8,
    const float* __restrict__ kbDT, const unsigned char* __restrict__ kbT8,
    unsigned short* __restrict__ Pb)
{
  const int tid  = threadIdx.x;
  const int lane = tid & 63;
  const int w    = tid >> 6;            // [0,4)
  const int l15  = lane & 15;
  const int quad = lane >> 4;

  const int id  = blockIdx.x;           // [0,2048)
  const int ox  = ((id & 7) << 1) | ((id >> 3) & 1);  // [0,16), XCD-paired
  const int iw  = (id >> 4) & 3;        // i-window (split) [0,4)
  const int by  = id >> 6;              // b-tile [0,32)

  const int o0 = ox * BM;               // 32-row o-tile base
  const int b0 = by * BN;
  const bool tail = (iw == 3);

  const int og = ox * 2 + (w >> 1);     // global 16-row o-group [0,32)
  const int bh = w & 1;                 // b-half (64 cols)

  // helper: load a 32-B fragment into i32x8
  auto load8 = [](const unsigned char* p) -> i32x8 {
    i32x4 lo = *reinterpret_cast<const i32x4*>(p);
    i32x4 hi = *reinterpret_cast<const i32x4*>(p + 16);
    i32x8 v;
    v[0] = lo[0]; v[1] = lo[1]; v[2] = lo[2]; v[3] = lo[3];
    v[4] = hi[0]; v[5] = hi[1]; v[6] = hi[2]; v[7] = hi[3];
    return v;
  };

  // ---- B fragments once (held for the whole kernel): 32 regs ----
  i32x8 bfr[4];
  #pragma unroll
  for (int nf = 0; nf < 4; ++nf)
    bfr[nf] = load8(Xf8 + (size_t)(b0 + bh * 64 + nf * 16 + l15) * IND_
                        + iw * 128 + quad * 32);

  // ---- A pointer: fragment-order, contiguous per og; +WT_DS per iter ----
  const unsigned char* aP =
      Wt + ((size_t)og * 4 + iw) * 2048 + lane * 32;

  // ---- dk pointer: kbDT[((d*32+by)*16+l15)*8 + bh*4]; +4096 per d ----
  const float* dP = kbDT + (((size_t)by * 16 + l15) * 8) + bh * 4;

  f32x4 acc[4], fin[4];
  #pragma unroll
  for (int nf = 0; nf < 4; ++nf) { acc[nf] = (f32x4)0.0f; fin[nf] = (f32x4)0.0f; }

  // 4 MFMAs (telescoping: acc never reset) + dk-scaled flush into fin
  auto mfma_flush = [&](const i32x8& a, const f32x4& q) {
    #pragma unroll
    for (int nf = 0; nf < 4; ++nf)
      acc[nf] = __builtin_amdgcn_mfma_scale_f32_16x16x128_f8f6f4(
          a, bfr[nf], acc[nf], 0, 0, 0, 0x7f7f7f7f, 0, 0x7f7f7f7f);
    #pragma unroll
    for (int nf = 0; nf < 4; ++nf)
      #pragma unroll
      for (int r = 0; r < 4; ++r)
        fin[nf][r] += q[nf] * acc[nf][r];
  };

  // ---- prologue: A(0), A(1) and q(0) in flight ----
  i32x8 a0 = load8(aP);
  i32x8 a1 = load8(aP + WT_DS);
  i32x8 a2;
  f32x4 qA = *reinterpret_cast<const f32x4*>(dP);
  f32x4 qB, qC;

  // ---- main loop: 24 iters in 8 unrolled-3 passes.
  // Invariant entering pass n (n = 3*pass): a0=A(n), a1=A(n+1), qA=q(n).
  // Every load is issued >= 1 iter before its use.
  for (int pass = 0; pass < 8; ++pass) {
    a2 = load8(aP + 2 * WT_DS);                        // A(n+2)
    qB = *reinterpret_cast<const f32x4*>(dP + 4096);   // q(n+1)
    mfma_flush(a0, qA);

    a0 = load8(aP + 3 * WT_DS);                        // A(n+3)
    qC = *reinterpret_cast<const f32x4*>(dP + 8192);   // q(n+2)
    mfma_flush(a1, qB);

    a1 = load8(aP + 4 * WT_DS);                        // A(n+4); last pass
    qA = *reinterpret_cast<const f32x4*>(dP + 12288);  //   overruns Wt (in-
    mfma_flush(a2, qC);                                //   ws, unused); q(n+3)

    aP += 3 * WT_DS;
    dP += 12288;
  }

  // ---- peeled iter 24 (a0 = A(24), qA = q(24)); bias-A for iw==3 ----
  if (tail) a1 = load8(Wt + WT_BIAS + (size_t)og * 2048 + lane * 32);
  mfma_flush(a0, qA);

  // ---- bias K-tail (iw==3): B = kbT8 fragments, accumulate into fin ----
  if (tail) {
    i32x8 bft[4];
    #pragma unroll
    for (int nf = 0; nf < 4; ++nf)
      bft[nf] = load8(kbT8 + (size_t)(b0 + bh * 64 + nf * 16 + l15) * 128
                           + quad * 32);
    #pragma unroll
    for (int nf = 0; nf < 4; ++nf)
      fin[nf] = __builtin_amdgcn_mfma_scale_f32_16x16x128_f8f6f4(
          a1, bft[nf], fin[nf], 0, 0, 0, 0x7f7f7f7f, 0, 0x7f7f7f7f);
  }

  // ---- store partial as bf16 ----
  unsigned short* Pz = Pb + (size_t)iw * NB * OUTD_;
  #pragma unroll
  for (int nf = 0; nf < 4; ++nf) {
    int bg = b0 + bh * 64 + nf * 16 + l15;
    int oo = o0 + (w >> 1) * 16 + quad * 4;
    u32x2 pk;
    pk[0] = pk_bf16(fin[nf][0], fin[nf][1]);
    pk[1] = pk_bf16(fin[nf][2], fin[nf][3]);
    *reinterpret_cast<u32x2*>(&Pz[(size_t)bg * OUTD_ + oo]) = pk;
  }
}

// ---------------------------------------------------------------------------
// epilogue: out[b][2+o..2+o+3] = relu(P0+P1+P2+P3)  (bias in K-tail)
// ---------------------------------------------------------------------------
__global__ __launch_bounds__(256) void epilogue_kernel(
    const unsigned short* __restrict__ Pb, float* __restrict__ out)
{
  const int idx = (blockIdx.x * 256 + threadIdx.x) * 4;   // < 4096*512
  const int b = idx >> 9;
  const int o = idx & 511;
  const size_t ps = (size_t)NB * OUTD_;
  float s[4] = {0.0f, 0.0f, 0.0f, 0.0f};
  #pragma unroll
  for (int z = 0; z < NSPL; ++z) {
    u16x4 v = *reinterpret_cast<const u16x4*>(&Pb[z * ps + idx]);
    #pragma unroll
    for (int e = 0; e < 4; ++e) s[e] += bf2f(v[e]);
  }
  float* op = out + (size_t)b * XCOLS + 2 + o;   // 8B-aligned
  float2 lo, hi;
  lo.x = s[0] > 0.0f ? s[0] : 0.0f;
  lo.y = s[1] > 0.0f ? s[1] : 0.0f;
  hi.x = s[2] > 0.0f ? s[2] : 0.0f;
  hi.y = s[3] > 0.0f ? s[3] : 0.0f;
  *(float2*)op = lo;
  *(float2*)(op + 2) = hi;
}

// ---------------------------------------------------------------------------
extern "C" void kernel_launch(void* const* d_in, const int* in_sizes, int n_in,
                              void* d_out, int out_size, void* d_ws, size_t ws_size,
                              hipStream_t stream) {
  const float* x    = (const float*)d_in[0];   // 4096 x 514
  const float* W    = (const float*)d_in[1];   // 512 x 512 x 25
  const float* bias = (const float*)d_in[2];   // 512 x 25
  float* out = (float*)d_out;
  char* ws = (char*)d_ws;

  // ws layout (bytes):
  //   Xf8 2,097,152 | Wt 6,619,136 | kbDT 25*4096*4 = 409,600
  //   kbT8 524,288 | Pb 4*4096*512*2 = 16,777,216   (total ~26.4 MB)
  const size_t xf_off  = 0;
  const size_t wf_off  = 2097152;
  const size_t kb_off  = wf_off + 6619136;
  const size_t kbt_off = kb_off + 409600;
  const size_t p_off   = kbt_off + (size_t)NB * 128;
  unsigned char* Xf8  = (unsigned char*)(ws + xf_off);
  unsigned char* Wt   = (unsigned char*)(ws + wf_off);
  float* kbDT         = (float*)(ws + kb_off);
  unsigned char* kbT8 = (unsigned char*)(ws + kbt_off);
  unsigned short* Pb  = (unsigned short*)(ws + p_off);

  prep_all_kernel<<<1536, 256, 0, stream>>>(x, W, bias, Xf8, kbDT, kbT8, Wt, out);
  gemm_mx_kernel<<<2048, 256, 0, stream>>>(Wt, Xf8, kbDT, kbT8, Pb);
  epilogue_kernel<<<(NB * OUTD_) / 1024, 256, 0, stream>>>(Pb, out);
}

// Round 12
// 123.569 us; speedup vs baseline: 1.3702x; 1.0446x over previous
//
#include <hip/hip_runtime.h>
#include <hip/hip_bf16.h>
#include <string.h>

// Problem constants
#define NB    4096      // batch rows
#define IND_  512       // feature dim
#define OUTD_ 512       // output dim (GEMM M, "o")
#define XCOLS 514       // P + IND
#define ND    25        // D^P
#define KTOT  12800     // IND_*ND

// Wt (fragment-order W) geometry: Wt[d][og][iw][lane][32]
//   d in [0,25), og in [0,32) (16-row o-groups), iw in [0,4), lane in [0,64)
//   d-stride = 32*4*2048 = 262144; bias block at WT_BIAS + og*2048
#define WT_DS   262144
#define WT_BIAS 6553600   // 25*262144; +32*2048 = 6,619,136 total

// GEMM tiling (v13: NO SPLIT-K. 32x128 block, 4 waves x (16o x 64b),
//              ALL-REGISTER, iw-loop inside the block, fused relu+store.
//              Epilogue kernel and Pb buffer deleted.)
#define BM 32
#define BN 128

// prep_w tiling (R18-proven v2 load stage)
#define PWI 64
#define PWO 4
#define PWC (PWO * ND)   // 100 columns (o_l*25 + d)
#define T8P 112          // tile8 padded byte stride

typedef float  f32x4  __attribute__((ext_vector_type(4)));
typedef int    i32x4  __attribute__((ext_vector_type(4)));
typedef int    i32x8  __attribute__((ext_vector_type(8)));
typedef unsigned int   u32x2 __attribute__((ext_vector_type(2)));

// Software fp32 -> OCP e4m3fn, RNE, for v >= 0 (all values < 1.2).
__device__ __forceinline__ unsigned char f2fp8(float v) {
  if (v < 0.015625f) {
    return (unsigned char)__float2int_rn(v * 512.0f);
  }
  unsigned int u = __float_as_uint(v);
  u += 0x7ffffu + ((u >> 20) & 1u);
  int e = (int)(u >> 23) - 127 + 7;
  unsigned int m = (u >> 20) & 7u;
  return (unsigned char)((e << 3) | m);
}

__device__ __forceinline__ float basis_f(float t, int j) {
  switch (j) {
    case 0: return 1.0f;
    case 1: return t;
    case 2: return t * t;
    case 3: { float r = t - 0.33f; r = r > 0.0f ? r : 0.0f; return r * r; }
    default:{ float r = t - 0.66f; r = r > 0.0f ? r : 0.0f; return r * r; }
  }
}

// ---------------------------------------------------------------------------
// prep_all v4 (R7/R8/R11-proven, unchanged): fragment-order Wt,
// fragment-order kbDT [d][bt][l15][nf], kbT8, bias block in Wt.
// ---------------------------------------------------------------------------
__global__ __launch_bounds__(256) void prep_all_kernel(
    const float* __restrict__ x, const float* __restrict__ W,
    const float* __restrict__ bias, unsigned char* __restrict__ Xf8,
    float* __restrict__ kbDT, unsigned char* __restrict__ kbT8,
    unsigned char* __restrict__ Wt, float* __restrict__ out)
{
  __shared__ unsigned char tile8[PWI * T8P];   // 7 KB
  const int bid = blockIdx.x;
  const int tid = threadIdx.x;

  if (bid < 512) {
    const int lane = tid & 63;
    #pragma unroll
    for (int rr = 0; rr < 2; ++rr) {
      const int b = bid * 8 + (tid >> 6) * 2 + rr;
      const float* xr = x + (size_t)b * XCOLS;
      const float* fp = xr + 2 + lane * 8;
      float2 a0 = *(const float2*)(fp + 0);
      float2 a1 = *(const float2*)(fp + 2);
      float2 a2 = *(const float2*)(fp + 4);
      float2 a3 = *(const float2*)(fp + 6);
      float xf[8] = {a0.x, a0.y, a1.x, a1.y, a2.x, a2.y, a3.x, a3.y};
      u32x2 pk;
      pk[0] = (unsigned int)f2fp8(xf[0]) | ((unsigned int)f2fp8(xf[1]) << 8) |
              ((unsigned int)f2fp8(xf[2]) << 16) | ((unsigned int)f2fp8(xf[3]) << 24);
      pk[1] = (unsigned int)f2fp8(xf[4]) | ((unsigned int)f2fp8(xf[5]) << 8) |
              ((unsigned int)f2fp8(xf[6]) << 16) | ((unsigned int)f2fp8(xf[7]) << 24);
      *reinterpret_cast<u32x2*>(Xf8 + (size_t)b * IND_ + lane * 8) = pk;

      float t0 = xr[0], t1 = xr[1];
      if (lane < 2) out[(size_t)b * XCOLS + lane] = (lane == 0) ? t0 : t1;
      {
        // telescoping difference dk_d = kv_d - kv_{d+1} (kv_25 := 0),
        // stored as kbDT[((d*32 + bt)*16 + (b&15))*8 + ((b>>4)&7)]
        int d1 = lane / 5, d2 = lane - d1 * 5;
        float kvd = basis_f(t0, d1) * basis_f(t1, d2);
        float kvn = 0.0f;
        if (lane < 24) {
          int e1 = (lane + 1) / 5, e2 = (lane + 1) - e1 * 5;
          kvn = basis_f(t0, e1) * basis_f(t1, e2);
        }
        if (lane < ND) {
          int bt = b >> 7, bl = b & 15, nf = (b >> 4) & 7;
          kbDT[(((size_t)lane * 32 + bt) * 16 + bl) * 8 + nf] = kvd - kvn;
        }
      }
      {
        int ta = 2 * lane, tb = 2 * lane + 1;
        unsigned char ba = 0, bb = 0;
        if (ta < ND) { int d1 = ta / 5, d2 = ta - d1 * 5;
                       ba = f2fp8(basis_f(t0, d1) * basis_f(t1, d2)); }
        if (tb < ND) { int d1 = tb / 5, d2 = tb - d1 * 5;
                       bb = f2fp8(basis_f(t0, d1) * basis_f(t1, d2)); }
        *(unsigned short*)(kbT8 + (size_t)b * 128 + 2 * lane) =
            (unsigned short)ba | ((unsigned short)bb << 8);
      }
    }
  } else {
    const int pw = bid - 512;
    const int i0 = (pw & 7) * PWI;
    const int o0 = (pw >> 3) * PWO;

    for (int t = tid; t < PWI * (PWC / 4); t += 256) {
      int il = t / (PWC / 4);
      int c4 = t - il * (PWC / 4);
      float4 v = *(const float4*)(W + ((size_t)(i0 + il) * OUTD_ + o0) * ND + c4 * 4);
      unsigned int pk = (unsigned int)f2fp8(v.x) | ((unsigned int)f2fp8(v.y) << 8) |
                        ((unsigned int)f2fp8(v.z) << 16) | ((unsigned int)f2fp8(v.w) << 24);
      *(unsigned int*)&tile8[il * T8P + c4 * 4] = pk;
    }
    __syncthreads();

    // byte-gather into FRAGMENT-ORDER Wt:
    //   dest(d, o, ib) = (((d*32 + o>>4)*4 + ib>>7)*2048
    //                    + ((ib&127)>>5)*512 + (o&15)*32 + (ib&31)
    for (int g = tid; g < PWC * (PWI / 8); g += 256) {
      int c  = g >> 3;
      int ig = g & 7;
      int d  = c % 25;
      int o_l = c / 25;
      unsigned long long v = 0;
      #pragma unroll
      for (int jj = 0; jj < 8; ++jj)
        v |= (unsigned long long)tile8[(ig * 8 + jj) * T8P + c] << (8 * jj);
      int o  = o0 + o_l;
      int ib = i0 + ig * 8;            // [0,512)
      int iw = ib >> 7;
      int wb = ib & 127;
      size_t dest = (((size_t)d * 32 + (o >> 4)) * 4 + iw) * 2048
                  + (size_t)(((wb >> 5) * 16 + (o & 15)) * 32 + (wb & 31));
      *reinterpret_cast<unsigned long long*>(Wt + dest) = v;
    }

    if ((pw & 7) == 0) {
      // bias block: fragment order at WT_BIAS + og*2048
      int o = o0 + (tid >> 6);
      int p = tid & 63;
      int ta = 2 * p, tb = 2 * p + 1;
      unsigned char ba = (ta < ND) ? f2fp8(bias[o * ND + ta]) : (unsigned char)0;
      unsigned char bb = (tb < ND) ? f2fp8(bias[o * ND + tb]) : (unsigned char)0;
      size_t dest = WT_BIAS + (size_t)(o >> 4) * 2048
                  + (size_t)(((ta >> 5) * 16 + (o & 15)) * 32 + (ta & 31));
      *(unsigned short*)(Wt + dest) =
          (unsigned short)ba | ((unsigned short)bb << 8);
    }
  }
}

// ---------------------------------------------------------------------------
// gemm_out v13: NO SPLIT-K — the v12 inner loop run 4x (iw = 0..3) inside
// one block, fin carried in f32 across all iw, fused bias + relu + direct
// f32 store to out.  Epilogue kernel, its launch gap, and the 33 MB Pb
// round-trip are deleted.
//
// R28 rationale: the clean-schedule matrix (R0..R11) converged to 42-45 us
// gemm with MfmaUtil 20-23% for EVERY structure (LDS-barrier / counted /
// B-reg / all-reg x occupancy x depth).  v12 was fully clean (WRITE == Pb,
// VGPR 76, no spill) and still 43.9 us -> the inner loop is at its
// HIP-source plateau; remaining wins are pipeline-structure (this) not
// schedule.  Per-CU serial work is IDENTICAL to v12 (208 block-iters:
// v12 = 8 blk/CU x 26, v13 = 2 blk/CU x 104).  Telescoping flush per iw
// (acc re-zeroed at iw boundary since B changes; fin = sum over iw of
// sum_d kv_d A_d^iw — algebraically identical to the split-K sum, and
// MORE accurate: no bf16 partial round-trip).
// Registers: same as v12 (~88 arch + 32 acc; v12 measured VGPR 76 clean)
// under the proven (256,3).  Grid 512 = 16 ox x 32 by = 2 blocks/CU,
// single round, no tail.  XCD map id&7 -> ox pair: per-XCD A set ~800 KB
// + Xf8 2 MB + kbDT/kbT8 ~1 MB, L2-resident.
// Prefetch overruns at iw-d boundaries (A(25..27), q(25..27)) read the
// bias block / kbDT / kbT8 regions — in-workspace, discarded.
// ---------------------------------------------------------------------------
__global__ __launch_bounds__(256, 3) void gemm_out_kernel(
    const unsigned char* __restrict__ Wt, const unsigned char* __restrict__ Xf8,
    const float* __restrict__ kbDT, const unsigned char* __restrict__ kbT8,
    float* __restrict__ out)
{
  const int tid  = threadIdx.x;
  const int lane = tid & 63;
  const int w    = tid >> 6;            // [0,4)
  const int l15  = lane & 15;
  const int quad = lane >> 4;

  const int id = blockIdx.x;            // [0,512)
  const int ox = ((id & 7) << 1) | ((id >> 3) & 1);   // [0,16), XCD-paired
  const int by = id >> 4;               // [0,32)

  const int o0 = ox * BM;               // 32-row o-tile base
  const int b0 = by * BN;

  const int og = ox * 2 + (w >> 1);     // global 16-row o-group [0,32)
  const int bh = w & 1;                 // b-half (64 cols)

  // helper: load a 32-B fragment into i32x8
  auto load8 = [](const unsigned char* p) -> i32x8 {
    i32x4 lo = *reinterpret_cast<const i32x4*>(p);
    i32x4 hi = *reinterpret_cast<const i32x4*>(p + 16);
    i32x8 v;
    v[0] = lo[0]; v[1] = lo[1]; v[2] = lo[2]; v[3] = lo[3];
    v[4] = hi[0]; v[5] = hi[1]; v[6] = hi[2]; v[7] = hi[3];
    return v;
  };

  f32x4 fin[4];
  #pragma unroll
  for (int nf = 0; nf < 4; ++nf) fin[nf] = (f32x4)0.0f;

  const float* dBase = kbDT + (((size_t)by * 16 + l15) * 8) + bh * 4;

  // ---- iw loop: 4 x the v12-proven 25-iter d-loop ----
  for (int iw = 0; iw < 4; ++iw) {
    // B fragments for this i-window: 32 regs
    i32x8 bfr[4];
    #pragma unroll
    for (int nf = 0; nf < 4; ++nf)
      bfr[nf] = load8(Xf8 + (size_t)(b0 + bh * 64 + nf * 16 + l15) * IND_
                          + iw * 128 + quad * 32);

    const unsigned char* aP = Wt + ((size_t)og * 4 + iw) * 2048 + lane * 32;
    const float* dP = dBase;

    f32x4 acc[4];
    #pragma unroll
    for (int nf = 0; nf < 4; ++nf) acc[nf] = (f32x4)0.0f;

    auto mfma_flush = [&](const i32x8& a, const f32x4& q) {
      #pragma unroll
      for (int nf = 0; nf < 4; ++nf)
        acc[nf] = __builtin_amdgcn_mfma_scale_f32_16x16x128_f8f6f4(
            a, bfr[nf], acc[nf], 0, 0, 0, 0x7f7f7f7f, 0, 0x7f7f7f7f);
      #pragma unroll
      for (int nf = 0; nf < 4; ++nf)
        #pragma unroll
        for (int r = 0; r < 4; ++r)
          fin[nf][r] += q[nf] * acc[nf][r];
    };

    // prologue: A(0), A(1), q(0) in flight
    i32x8 a0 = load8(aP);
    i32x8 a1 = load8(aP + WT_DS);
    i32x8 a2;
    f32x4 qA = *reinterpret_cast<const f32x4*>(dP);
    f32x4 qB, qC;

    // 24 iters in 8 unrolled-3 passes; every load >= 1 iter ahead of use.
    for (int pass = 0; pass < 8; ++pass) {
      a2 = load8(aP + 2 * WT_DS);                        // A(n+2)
      qB = *reinterpret_cast<const f32x4*>(dP + 4096);   // q(n+1)
      mfma_flush(a0, qA);

      a0 = load8(aP + 3 * WT_DS);                        // A(n+3)
      qC = *reinterpret_cast<const f32x4*>(dP + 8192);   // q(n+2)
      mfma_flush(a1, qB);

      a1 = load8(aP + 4 * WT_DS);                        // A(n+4); overruns
      qA = *reinterpret_cast<const f32x4*>(dP + 12288);  //   at d>24: in-ws,
      mfma_flush(a2, qC);                                //   unused

      aP += 3 * WT_DS;
      dP += 12288;
    }

    // peeled iter 24 (a0 = A(24), qA = q(24))
    mfma_flush(a0, qA);
  }

  // ---- bias K-tail (once): A = bias block, B = kbT8, kv = 1 -> into fin
  {
    i32x8 ab = load8(Wt + WT_BIAS + (size_t)og * 2048 + lane * 32);
    i32x8 bft[4];
    #pragma unroll
    for (int nf = 0; nf < 4; ++nf)
      bft[nf] = load8(kbT8 + (size_t)(b0 + bh * 64 + nf * 16 + l15) * 128
                           + quad * 32);
    #pragma unroll
    for (int nf = 0; nf < 4; ++nf)
      fin[nf] = __builtin_amdgcn_mfma_scale_f32_16x16x128_f8f6f4(
          ab, bft[nf], fin[nf], 0, 0, 0, 0x7f7f7f7f, 0, 0x7f7f7f7f);
  }

  // ---- fused relu + direct f32 store to out ----
  #pragma unroll
  for (int nf = 0; nf < 4; ++nf) {
    int bg = b0 + bh * 64 + nf * 16 + l15;
    int oo = o0 + (w >> 1) * 16 + quad * 4;
    float* op = out + (size_t)bg * XCOLS + 2 + oo;   // 8B-aligned
    float2 lo, hi;
    lo.x = fin[nf][0] > 0.0f ? fin[nf][0] : 0.0f;
    lo.y = fin[nf][1] > 0.0f ? fin[nf][1] : 0.0f;
    hi.x = fin[nf][2] > 0.0f ? fin[nf][2] : 0.0f;
    hi.y = fin[nf][3] > 0.0f ? fin[nf][3] : 0.0f;
    *(float2*)op = lo;
    *(float2*)(op + 2) = hi;
  }
}

// ---------------------------------------------------------------------------
extern "C" void kernel_launch(void* const* d_in, const int* in_sizes, int n_in,
                              void* d_out, int out_size, void* d_ws, size_t ws_size,
                              hipStream_t stream) {
  const float* x    = (const float*)d_in[0];   // 4096 x 514
  const float* W    = (const float*)d_in[1];   // 512 x 512 x 25
  const float* bias = (const float*)d_in[2];   // 512 x 25
  float* out = (float*)d_out;
  char* ws = (char*)d_ws;

  // ws layout (bytes):
  //   Xf8 2,097,152 | Wt 6,619,136 | kbDT 25*4096*4 = 409,600
  //   kbT8 524,288   (Pb deleted — no split-K)
  const size_t xf_off  = 0;
  const size_t wf_off  = 2097152;
  const size_t kb_off  = wf_off + 6619136;
  const size_t kbt_off = kb_off + 409600;
  unsigned char* Xf8  = (unsigned char*)(ws + xf_off);
  unsigned char* Wt   = (unsigned char*)(ws + wf_off);
  float* kbDT         = (float*)(ws + kb_off);
  unsigned char* kbT8 = (unsigned char*)(ws + kbt_off);

  prep_all_kernel<<<1536, 256, 0, stream>>>(x, W, bias, Xf8, kbDT, kbT8, Wt, out);
  gemm_out_kernel<<<512, 256, 0, stream>>>(Wt, Xf8, kbDT, kbT8, out);
}

// Round 13
// 118.367 us; speedup vs baseline: 1.4305x; 1.0439x over previous
//
#include <hip/hip_runtime.h>
#include <hip/hip_bf16.h>
#include <string.h>

// Problem constants
#define NB    4096      // batch rows
#define IND_  512       // feature dim
#define OUTD_ 512       // output dim (GEMM M, "o")
#define XCOLS 514       // P + IND
#define ND    25        // D^P
#define KTOT  12800     // IND_*ND

// Wt (fragment-order W) geometry: Wt[d][og][iw][lane][32]
//   d in [0,25), og in [0,32) (16-row o-groups), iw in [0,4), lane in [0,64)
//   d-stride = 32*4*2048 = 262144; bias block at WT_BIAS + og*2048
#define WT_DS   262144
#define WT_BIAS 6553600   // 25*262144; +32*2048 = 6,619,136 total

// GEMM tiling (v14: v13 fused no-split-K structure + UNCHAINED acc and
//              DEFERRED flush — no cross-iter MFMA dependency)
#define BM 32
#define BN 128

// prep_w tiling (R18-proven v2 load stage)
#define PWI 64
#define PWO 4
#define PWC (PWO * ND)   // 100 columns (o_l*25 + d)
#define T8P 112          // tile8 padded byte stride

typedef float  f32x4  __attribute__((ext_vector_type(4)));
typedef int    i32x4  __attribute__((ext_vector_type(4)));
typedef int    i32x8  __attribute__((ext_vector_type(8)));
typedef unsigned int   u32x2 __attribute__((ext_vector_type(2)));

// Software fp32 -> OCP e4m3fn, RNE, for v >= 0 (all values < 1.2).
__device__ __forceinline__ unsigned char f2fp8(float v) {
  if (v < 0.015625f) {
    return (unsigned char)__float2int_rn(v * 512.0f);
  }
  unsigned int u = __float_as_uint(v);
  u += 0x7ffffu + ((u >> 20) & 1u);
  int e = (int)(u >> 23) - 127 + 7;
  unsigned int m = (u >> 20) & 7u;
  return (unsigned char)((e << 3) | m);
}

__device__ __forceinline__ float basis_f(float t, int j) {
  switch (j) {
    case 0: return 1.0f;
    case 1: return t;
    case 2: return t * t;
    case 3: { float r = t - 0.33f; r = r > 0.0f ? r : 0.0f; return r * r; }
    default:{ float r = t - 0.66f; r = r > 0.0f ? r : 0.0f; return r * r; }
  }
}

// ---------------------------------------------------------------------------
// prep_all v5: identical to v4 except kbDT now stores kv_d ITSELF (not the
// telescoping difference) — v14's gemm flushes fin += kv_d * acc_d directly
// with unchained acc.  Layout unchanged: kbKV[((d*32+bt)*16+bl)*8+nf].
// ---------------------------------------------------------------------------
__global__ __launch_bounds__(256) void prep_all_kernel(
    const float* __restrict__ x, const float* __restrict__ W,
    const float* __restrict__ bias, unsigned char* __restrict__ Xf8,
    float* __restrict__ kbKV, unsigned char* __restrict__ kbT8,
    unsigned char* __restrict__ Wt, float* __restrict__ out)
{
  __shared__ unsigned char tile8[PWI * T8P];   // 7 KB
  const int bid = blockIdx.x;
  const int tid = threadIdx.x;

  if (bid < 512) {
    const int lane = tid & 63;
    #pragma unroll
    for (int rr = 0; rr < 2; ++rr) {
      const int b = bid * 8 + (tid >> 6) * 2 + rr;
      const float* xr = x + (size_t)b * XCOLS;
      const float* fp = xr + 2 + lane * 8;
      float2 a0 = *(const float2*)(fp + 0);
      float2 a1 = *(const float2*)(fp + 2);
      float2 a2 = *(const float2*)(fp + 4);
      float2 a3 = *(const float2*)(fp + 6);
      float xf[8] = {a0.x, a0.y, a1.x, a1.y, a2.x, a2.y, a3.x, a3.y};
      u32x2 pk;
      pk[0] = (unsigned int)f2fp8(xf[0]) | ((unsigned int)f2fp8(xf[1]) << 8) |
              ((unsigned int)f2fp8(xf[2]) << 16) | ((unsigned int)f2fp8(xf[3]) << 24);
      pk[1] = (unsigned int)f2fp8(xf[4]) | ((unsigned int)f2fp8(xf[5]) << 8) |
              ((unsigned int)f2fp8(xf[6]) << 16) | ((unsigned int)f2fp8(xf[7]) << 24);
      *reinterpret_cast<u32x2*>(Xf8 + (size_t)b * IND_ + lane * 8) = pk;

      float t0 = xr[0], t1 = xr[1];
      if (lane < 2) out[(size_t)b * XCOLS + lane] = (lane == 0) ? t0 : t1;
      {
        // kv_d stored directly (v14: unchained acc, direct weighting)
        int d1 = lane / 5, d2 = lane - d1 * 5;
        float kvd = basis_f(t0, d1) * basis_f(t1, d2);
        if (lane < ND) {
          int bt = b >> 7, bl = b & 15, nf = (b >> 4) & 7;
          kbKV[(((size_t)lane * 32 + bt) * 16 + bl) * 8 + nf] = kvd;
        }
      }
      {
        int ta = 2 * lane, tb = 2 * lane + 1;
        unsigned char ba = 0, bb = 0;
        if (ta < ND) { int d1 = ta / 5, d2 = ta - d1 * 5;
                       ba = f2fp8(basis_f(t0, d1) * basis_f(t1, d2)); }
        if (tb < ND) { int d1 = tb / 5, d2 = tb - d1 * 5;
                       bb = f2fp8(basis_f(t0, d1) * basis_f(t1, d2)); }
        *(unsigned short*)(kbT8 + (size_t)b * 128 + 2 * lane) =
            (unsigned short)ba | ((unsigned short)bb << 8);
      }
    }
  } else {
    const int pw = bid - 512;
    const int i0 = (pw & 7) * PWI;
    const int o0 = (pw >> 3) * PWO;

    for (int t = tid; t < PWI * (PWC / 4); t += 256) {
      int il = t / (PWC / 4);
      int c4 = t - il * (PWC / 4);
      float4 v = *(const float4*)(W + ((size_t)(i0 + il) * OUTD_ + o0) * ND + c4 * 4);
      unsigned int pk = (unsigned int)f2fp8(v.x) | ((unsigned int)f2fp8(v.y) << 8) |
                        ((unsigned int)f2fp8(v.z) << 16) | ((unsigned int)f2fp8(v.w) << 24);
      *(unsigned int*)&tile8[il * T8P + c4 * 4] = pk;
    }
    __syncthreads();

    // byte-gather into FRAGMENT-ORDER Wt:
    //   dest(d, o, ib) = (((d*32 + o>>4)*4 + ib>>7)*2048
    //                    + ((ib&127)>>5)*512 + (o&15)*32 + (ib&31)
    for (int g = tid; g < PWC * (PWI / 8); g += 256) {
      int c  = g >> 3;
      int ig = g & 7;
      int d  = c % 25;
      int o_l = c / 25;
      unsigned long long v = 0;
      #pragma unroll
      for (int jj = 0; jj < 8; ++jj)
        v |= (unsigned long long)tile8[(ig * 8 + jj) * T8P + c] << (8 * jj);
      int o  = o0 + o_l;
      int ib = i0 + ig * 8;            // [0,512)
      int iw = ib >> 7;
      int wb = ib & 127;
      size_t dest = (((size_t)d * 32 + (o >> 4)) * 4 + iw) * 2048
                  + (size_t)(((wb >> 5) * 16 + (o & 15)) * 32 + (wb & 31));
      *reinterpret_cast<unsigned long long*>(Wt + dest) = v;
    }

    if ((pw & 7) == 0) {
      // bias block: fragment order at WT_BIAS + og*2048
      int o = o0 + (tid >> 6);
      int p = tid & 63;
      int ta = 2 * p, tb = 2 * p + 1;
      unsigned char ba = (ta < ND) ? f2fp8(bias[o * ND + ta]) : (unsigned char)0;
      unsigned char bb = (tb < ND) ? f2fp8(bias[o * ND + tb]) : (unsigned char)0;
      size_t dest = WT_BIAS + (size_t)(o >> 4) * 2048
                  + (size_t)(((ta >> 5) * 16 + (o & 15)) * 32 + (ta & 31));
      *(unsigned short*)(Wt + dest) =
          (unsigned short)ba | ((unsigned short)bb << 8);
    }
  }
}

// ---------------------------------------------------------------------------
// gemm_out v14: v13 fused structure + UNCHAINED acc + DEFERRED flush.
//
// R29 theory: across ALL 11 schedules (LDS x all-reg x occupancy x depth),
// gemm sat at 42-45 us, 4x the 11.5 us MFMA floor, MfmaUtil ~22%.  The one
// invariant: acc chained across K-iters (acc = mfma(a,b,acc)) — only 4-16
// independent MFMA chains per SIMD — AND the VALU flush reading acc
// immediately after the MFMAs (wave stalls the full MFMA completion
// latency every iter).  Since we flush every iter anyway, telescoping buys
// nothing: compute acc(n) = mfma(a,b,0) (iters fully INDEPENDENT) and
// flush fin += kv(n)*acc(n) ONE ITER LATE (acc(n) consumed after iter
// n+1's MFMAs are issued — a full iteration of latency cover).
// 2-unroll passes (parity-stable accA/accB), depth-2+ A prefetch
// (a0/a1 + in-pass reload = 2-iter lead), q prefetched 2 iters ahead.
// Prefetch overruns (A(25),A(26), q(25)) land in kbKV/kbT8 — in-ws,
// discarded.  Regs: bfr 32 + a 16 + acc 32 + fin 16 + q 16 + Z/ptrs ~14
// -> ~95 arch + 48 accum, fits (256,3) cap 170 clean (R11: no spill).
// Everything else v13-proven: iw-loop, fused bias tail + relu + f32 store.
// ---------------------------------------------------------------------------
__global__ __launch_bounds__(256, 3) void gemm_out_kernel(
    const unsigned char* __restrict__ Wt, const unsigned char* __restrict__ Xf8,
    const float* __restrict__ kbKV, const unsigned char* __restrict__ kbT8,
    float* __restrict__ out)
{
  const int tid  = threadIdx.x;
  const int lane = tid & 63;
  const int w    = tid >> 6;            // [0,4)
  const int l15  = lane & 15;
  const int quad = lane >> 4;

  const int id = blockIdx.x;            // [0,512)
  const int ox = ((id & 7) << 1) | ((id >> 3) & 1);   // [0,16), XCD-paired
  const int by = id >> 4;               // [0,32)

  const int o0 = ox * BM;               // 32-row o-tile base
  const int b0 = by * BN;

  const int og = ox * 2 + (w >> 1);     // global 16-row o-group [0,32)
  const int bh = w & 1;                 // b-half (64 cols)

  // helper: load a 32-B fragment into i32x8
  auto load8 = [](const unsigned char* p) -> i32x8 {
    i32x4 lo = *reinterpret_cast<const i32x4*>(p);
    i32x4 hi = *reinterpret_cast<const i32x4*>(p + 16);
    i32x8 v;
    v[0] = lo[0]; v[1] = lo[1]; v[2] = lo[2]; v[3] = lo[3];
    v[4] = hi[0]; v[5] = hi[1]; v[6] = hi[2]; v[7] = hi[3];
    return v;
  };

  f32x4 fin[4];
  #pragma unroll
  for (int nf = 0; nf < 4; ++nf) fin[nf] = (f32x4)0.0f;

  const f32x4 Z = (f32x4)0.0f;
  const float* dBase = kbKV + (((size_t)by * 16 + l15) * 8) + bh * 4;

  // ---- iw loop: 4 x 25-iter d-loop, unchained acc, deferred flush ----
  for (int iw = 0; iw < 4; ++iw) {
    // B fragments for this i-window: 32 regs
    i32x8 bfr[4];
    #pragma unroll
    for (int nf = 0; nf < 4; ++nf)
      bfr[nf] = load8(Xf8 + (size_t)(b0 + bh * 64 + nf * 16 + l15) * IND_
                          + iw * 128 + quad * 32);

    const unsigned char* aP = Wt + ((size_t)og * 4 + iw) * 2048 + lane * 32;
    const float* dP = dBase;

    // 4 independent MFMAs, C = 0 (no cross-iter chain)
    f32x4 accA[4], accB[4];
    auto mfma4A = [&](const i32x8& a) {
      #pragma unroll
      for (int nf = 0; nf < 4; ++nf)
        accA[nf] = __builtin_amdgcn_mfma_scale_f32_16x16x128_f8f6f4(
            a, bfr[nf], Z, 0, 0, 0, 0x7f7f7f7f, 0, 0x7f7f7f7f);
    };
    auto mfma4B = [&](const i32x8& a) {
      #pragma unroll
      for (int nf = 0; nf < 4; ++nf)
        accB[nf] = __builtin_amdgcn_mfma_scale_f32_16x16x128_f8f6f4(
            a, bfr[nf], Z, 0, 0, 0, 0x7f7f7f7f, 0, 0x7f7f7f7f);
    };
    auto flushA = [&](const f32x4& q) {
      #pragma unroll
      for (int nf = 0; nf < 4; ++nf)
        #pragma unroll
        for (int r = 0; r < 4; ++r)
          fin[nf][r] += q[nf] * accA[nf][r];
    };
    auto flushB = [&](const f32x4& q) {
      #pragma unroll
      for (int nf = 0; nf < 4; ++nf)
        #pragma unroll
        for (int r = 0; r < 4; ++r)
          fin[nf][r] += q[nf] * accB[nf][r];
    };

    // prologue: A(0), A(1); q(0), q(1)
    i32x8 a0 = load8(aP);
    i32x8 a1 = load8(aP + WT_DS);
    f32x4 qA = *reinterpret_cast<const f32x4*>(dP);
    f32x4 qB = *reinterpret_cast<const f32x4*>(dP + 4096);

    // peel iter 0: acc(0) into accA; reload a0 <- A(2)
    mfma4A(a0);
    a0 = load8(aP + 2 * WT_DS);

    // 12 passes x 2 iters: n = 2p+1 (accB), 2p+2 (accA).
    // Flush of acc(n) happens AFTER iter n+1's MFMAs are issued.
    for (int p = 0; p < 12; ++p) {
      // iter 2p+1:
      mfma4B(a1);                                        // A(2p+1)
      a1 = load8(aP + 3 * WT_DS);                        // A(2p+3)
      f32x4 qC = *reinterpret_cast<const f32x4*>(dP + 2 * 4096);  // q(2p+2)
      flushA(qA);                                        // acc(2p), covered
      // iter 2p+2:
      mfma4A(a0);                                        // A(2p+2)
      a0 = load8(aP + 4 * WT_DS);                        // A(2p+4); p=11 ->
      f32x4 qD = *reinterpret_cast<const f32x4*>(dP + 3 * 4096);  //  in-ws
      flushB(qB);                                        // acc(2p+1)
      qA = qC; qB = qD;
      aP += 2 * WT_DS;
      dP += 2 * 4096;
    }
    // epilogue: acc(24) in accA, qA = q(24)
    flushA(qA);
  }

  // ---- bias K-tail (once): A = bias block, B = kbT8, kv = 1 -> into fin
  {
    i32x8 ab = load8(Wt + WT_BIAS + (size_t)og * 2048 + lane * 32);
    i32x8 bft[4];
    #pragma unroll
    for (int nf = 0; nf < 4; ++nf)
      bft[nf] = load8(kbT8 + (size_t)(b0 + bh * 64 + nf * 16 + l15) * 128
                           + quad * 32);
    #pragma unroll
    for (int nf = 0; nf < 4; ++nf)
      fin[nf] = __builtin_amdgcn_mfma_scale_f32_16x16x128_f8f6f4(
          ab, bft[nf], fin[nf], 0, 0, 0, 0x7f7f7f7f, 0, 0x7f7f7f7f);
  }

  // ---- fused relu + direct f32 store to out ----
  #pragma unroll
  for (int nf = 0; nf < 4; ++nf) {
    int bg = b0 + bh * 64 + nf * 16 + l15;
    int oo = o0 + (w >> 1) * 16 + quad * 4;
    float* op = out + (size_t)bg * XCOLS + 2 + oo;   // 8B-aligned
    float2 lo, hi;
    lo.x = fin[nf][0] > 0.0f ? fin[nf][0] : 0.0f;
    lo.y = fin[nf][1] > 0.0f ? fin[nf][1] : 0.0f;
    hi.x = fin[nf][2] > 0.0f ? fin[nf][2] : 0.0f;
    hi.y = fin[nf][3] > 0.0f ? fin[nf][3] : 0.0f;
    *(float2*)op = lo;
    *(float2*)(op + 2) = hi;
  }
}

// ---------------------------------------------------------------------------
extern "C" void kernel_launch(void* const* d_in, const int* in_sizes, int n_in,
                              void* d_out, int out_size, void* d_ws, size_t ws_size,
                              hipStream_t stream) {
  const float* x    = (const float*)d_in[0];   // 4096 x 514
  const float* W    = (const float*)d_in[1];   // 512 x 512 x 25
  const float* bias = (const float*)d_in[2];   // 512 x 25
  float* out = (float*)d_out;
  char* ws = (char*)d_ws;

  // ws layout (bytes):
  //   Xf8 2,097,152 | Wt 6,619,136 | kbKV 25*4096*4 = 409,600
  //   kbT8 524,288   (no split-K, no Pb)
  const size_t xf_off  = 0;
  const size_t wf_off  = 2097152;
  const size_t kb_off  = wf_off + 6619136;
  const size_t kbt_off = kb_off + 409600;
  unsigned char* Xf8  = (unsigned char*)(ws + xf_off);
  unsigned char* Wt   = (unsigned char*)(ws + wf_off);
  float* kbKV         = (float*)(ws + kb_off);
  unsigned char* kbT8 = (unsigned char*)(ws + kbt_off);

  prep_all_kernel<<<1536, 256, 0, stream>>>(x, W, bias, Xf8, kbKV, kbT8, Wt, out);
  gemm_out_kernel<<<512, 256, 0, stream>>>(Wt, Xf8, kbKV, kbT8, out);
}